// Round 3
// baseline (541.412 us; speedup 1.0000x reference)
//
#include <hip/hip_runtime.h>
#include <hip/hip_bf16.h>
#include <type_traits>

// Problem constants: B=4, S=1024, D=2048, H=16, G=2, HD=128
typedef __attribute__((ext_vector_type(8))) __bf16 bf16x8;
typedef __attribute__((ext_vector_type(4))) float floatx4;

__device__ inline floatx4 mfma_bf16(bf16x8 a, bf16x8 b, floatx4 c) {
    return __builtin_amdgcn_mfma_f32_16x16x32_bf16(a, b, c, 0, 0, 0);
}

__device__ inline void g2l16(const __hip_bfloat16* g, __hip_bfloat16* l) {
    __builtin_amdgcn_global_load_lds(
        (const __attribute__((address_space(1))) void*)g,
        (__attribute__((address_space(3))) void*)l, 16, 0, 0);
}

// ---------------- cast f32 -> bf16 (vectorized) ----------------
__global__ void cast_f32_bf16_k(const float* __restrict__ in,
                                __hip_bfloat16* __restrict__ out, int n4) {
    int i = blockIdx.x * blockDim.x + threadIdx.x;
    if (i < n4) {
        float4 v = ((const float4*)in)[i];
        ushort4 u;
        __hip_bfloat16 a0 = __float2bfloat16(v.x), a1 = __float2bfloat16(v.y);
        __hip_bfloat16 a2 = __float2bfloat16(v.z), a3 = __float2bfloat16(v.w);
        u.x = *(unsigned short*)&a0; u.y = *(unsigned short*)&a1;
        u.z = *(unsigned short*)&a2; u.w = *(unsigned short*)&a3;
        ((ushort4*)out)[i] = u;
    }
}

// ---------------- transpose + cast: W(R,C) f32 -> Wt(C,R) bf16 ----------------
__global__ void transpose_cast_k(const float* __restrict__ W,
                                 __hip_bfloat16* __restrict__ Wt,
                                 int R, int C, int row_off) {
    __shared__ float tile[32][33];
    int c0 = blockIdx.x * 32, r0 = blockIdx.y * 32;
    int tx = threadIdx.x & 31, ty0 = threadIdx.x >> 5;
#pragma unroll
    for (int i = 0; i < 4; i++) {
        int ty = ty0 + i * 8;
        tile[ty][tx] = W[(size_t)(r0 + ty) * C + c0 + tx];
    }
    __syncthreads();
#pragma unroll
    for (int i = 0; i < 4; i++) {
        int ty = ty0 + i * 8;
        Wt[(size_t)(row_off + c0 + ty) * R + r0 + tx] = __float2bfloat16(tile[tx][ty]);
    }
}

__global__ void concat_bias_k(const float* __restrict__ a,
                              const float* __restrict__ b,
                              float* __restrict__ out) {
    int i = threadIdx.x;
    out[i] = (i < 256) ? a[i] : b[i - 256];
}

// ---------------- GEMM: C(M,N) = A(M,K) @ Bt(N,K)^T + bias, bf16 in, OUT_T out ----
template <typename OUT_T>
__global__ __launch_bounds__(256) void gemm_bt_k(
    const __hip_bfloat16* __restrict__ A,
    const __hip_bfloat16* __restrict__ Bt,
    const float* __restrict__ bias,
    OUT_T* __restrict__ C,
    int M, int N, int K) {
    __shared__ alignas(16) __hip_bfloat16 As[128 * 32];
    __shared__ alignas(16) __hip_bfloat16 Bs[128 * 32];
    const int t = threadIdx.x;
    const int lane = t & 63;
    const int w = t >> 6;
    const int wm = w & 1, wn = w >> 1;
    const int quad = lane >> 4, l16 = lane & 15;
    const int bm = blockIdx.y, bn = blockIdx.x;
    const int r_ = t >> 2, kc_ = t & 3;

    const __hip_bfloat16* gA = A + (size_t)(bm * 128 + r_) * K + kc_ * 8;
    const __hip_bfloat16* gB = Bt + (size_t)(bn * 128 + r_) * K + kc_ * 8;

    floatx4 acc[4][4] = {};

    for (int kt = 0; kt < K; kt += 32) {
        g2l16(gA + kt, As + t * 8);
        g2l16(gA + kt + (size_t)64 * K, As + (t + 256) * 8);
        g2l16(gB + kt, Bs + t * 8);
        g2l16(gB + kt + (size_t)64 * K, Bs + (t + 256) * 8);
        __syncthreads();
        bf16x8 af[4], bfr[4];
#pragma unroll
        for (int mi = 0; mi < 4; mi++)
            af[mi] = *(const bf16x8*)(As + (wm * 64 + mi * 16 + l16) * 32 + quad * 8);
#pragma unroll
        for (int ni = 0; ni < 4; ni++)
            bfr[ni] = *(const bf16x8*)(Bs + (wn * 64 + ni * 16 + l16) * 32 + quad * 8);
#pragma unroll
        for (int mi = 0; mi < 4; mi++)
#pragma unroll
            for (int ni = 0; ni < 4; ni++)
                acc[mi][ni] = mfma_bf16(af[mi], bfr[ni], acc[mi][ni]);
        __syncthreads();
    }

#pragma unroll
    for (int mi = 0; mi < 4; mi++) {
        int row0 = bm * 128 + wm * 64 + mi * 16 + quad * 4;
#pragma unroll
        for (int ni = 0; ni < 4; ni++) {
            int col = bn * 128 + wn * 64 + ni * 16 + l16;
            float bv = bias[col];
#pragma unroll
            for (int r = 0; r < 4; r++) {
                float v = acc[mi][ni][r] + bv;
                if constexpr (std::is_same<OUT_T, float>::value)
                    C[(size_t)(row0 + r) * N + col] = v;
                else
                    C[(size_t)(row0 + r) * N + col] = __float2bfloat16(v);
            }
        }
    }
}

// ---------------- RoPE + relayout ----------------
__global__ void rope_k(const __hip_bfloat16* __restrict__ in,
                       __hip_bfloat16* __restrict__ out,
                       int NH, int in_ld, float scale) {
    int idx = blockIdx.x * 256 + threadIdx.x;
    int j = idx & 63;
    int s = (idx >> 6) & 1023;
    int bh = idx >> 16;
    int b = bh / NH, h = bh % NH;
    float inv_freq = powf(10000.f, -(float)j * (1.f / 64.f));
    float ang = (float)s * inv_freq;
    float cs = cosf(ang), sn = sinf(ang);
    const __hip_bfloat16* ip = in + (size_t)(b * 1024 + s) * in_ld + h * 128;
    float q0 = __bfloat162float(ip[j]);
    float q1 = __bfloat162float(ip[j + 64]);
    __hip_bfloat16* op = out + ((size_t)(b * NH + h) * 1024 + s) * 128;
    op[j]      = __float2bfloat16((q0 * cs - q1 * sn) * scale);
    op[j + 64] = __float2bfloat16((q1 * cs + q0 * sn) * scale);
}

// V part of KVlin (cols 256..511) -> VT (B, G, 128, 1024)
__global__ void transpose_v_k(const __hip_bfloat16* __restrict__ KVlin,
                              __hip_bfloat16* __restrict__ VT) {
    __shared__ __hip_bfloat16 tile[32][33];
    int bg = blockIdx.z;
    int b = bg >> 1, g = bg & 1;
    int s0 = blockIdx.y * 32, d0 = blockIdx.x * 32;
    int tx = threadIdx.x & 31, ty0 = threadIdx.x >> 5;
#pragma unroll
    for (int i = 0; i < 4; i++) {
        int ty = ty0 + i * 8;
        tile[ty][tx] = KVlin[(size_t)(b * 1024 + s0 + ty) * 512 + 256 + g * 128 + d0 + tx];
    }
    __syncthreads();
#pragma unroll
    for (int i = 0; i < 4; i++) {
        int ty = ty0 + i * 8;
        VT[((size_t)(b * 2 + g) * 128 + d0 + ty) * 1024 + s0 + tx] = tile[tx][ty];
    }
}

// ---------------- flash attention v3 ----------------
// 16 q-rows per wave, 64 per block; grid (64, 16) = 1024 blocks -> 4 blocks/CU
// (v2 was grid-limited to 2 blocks/CU = 22% occupancy; MfmaUtil 10.5%).
// No max-subtraction (scores bounded |s|<~1 by construction), lane-local l sum,
// no block barrier: per-wave double-buffered LDS P tile, in-order DS ops.
__global__ __launch_bounds__(256, 4) void attn_k(
    const __hip_bfloat16* __restrict__ Qb,
    const __hip_bfloat16* __restrict__ Kb,
    const __hip_bfloat16* __restrict__ VT,
    __hip_bfloat16* __restrict__ AO) {
    constexpr int PLD = 40;   // padded P row stride (bf16): 80 B
    __shared__ alignas(16) __hip_bfloat16 Plds[4][2][16 * PLD];
    int bh = blockIdx.x;          // b*16 + h
    int b = bh >> 4, h = bh & 15, g = h >> 3;
    int t = threadIdx.x, lane = t & 63, w = t >> 6;
    int quad = lane >> 4, l16 = lane & 15;
    int q0 = blockIdx.y * 64 + w * 16;

    const __hip_bfloat16* Qp = Qb + ((size_t)bh * 1024 + q0 + l16) * 128 + quad * 8;
    bf16x8 aq[4];
#pragma unroll
    for (int kc = 0; kc < 4; kc++)
        aq[kc] = *(const bf16x8*)(Qp + kc * 32);

    const __hip_bfloat16* Kbase = Kb + ((size_t)(b * 2 + g) * 1024 + l16) * 128 + quad * 8;
    const __hip_bfloat16* Vbase = VT + ((size_t)(b * 2 + g) * 128 + l16) * 1024 + quad * 8;

    float l_part[4] = {};
    floatx4 o[8] = {};

    int buf = 0;
#pragma unroll 2
    for (int kv = 0; kv < 1024; kv += 32, buf ^= 1) {
        floatx4 s[2] = {};
#pragma unroll
        for (int nj = 0; nj < 2; nj++)
#pragma unroll
            for (int kc = 0; kc < 4; kc++) {
                bf16x8 kb = *(const bf16x8*)(Kbase + (size_t)(kv + nj * 16) * 128 + kc * 32);
                s[nj] = mfma_bf16(aq[kc], kb, s[nj]);
            }
        __hip_bfloat16* pl = Plds[w][buf];
#pragma unroll
        for (int nj = 0; nj < 2; nj++)
#pragma unroll
            for (int r = 0; r < 4; r++) {
                float p = __expf(s[nj][r]);
                l_part[r] += p;
                pl[(quad * 4 + r) * PLD + nj * 16 + l16] = __float2bfloat16(p);
            }
        asm volatile("s_waitcnt lgkmcnt(0)");
        bf16x8 ap = *(const bf16x8*)(pl + (size_t)l16 * PLD + quad * 8);
#pragma unroll
        for (int ni = 0; ni < 8; ni++) {
            bf16x8 vb = *(const bf16x8*)(Vbase + (size_t)(ni * 16) * 1024 + kv);
            o[ni] = mfma_bf16(ap, vb, o[ni]);
        }
    }

#pragma unroll
    for (int r = 0; r < 4; r++) {
        float sum = l_part[r];
        sum += __shfl_xor(sum, 1);
        sum += __shfl_xor(sum, 2);
        sum += __shfl_xor(sum, 4);
        sum += __shfl_xor(sum, 8);
        float inv = 1.f / sum;
        size_t srow = (size_t)b * 1024 + q0 + quad * 4 + r;
#pragma unroll
        for (int ni = 0; ni < 8; ni++)
            AO[srow * 2048 + h * 128 + ni * 16 + l16] =
                __float2bfloat16(o[ni][r] * inv);
    }
}

extern "C" void kernel_launch(void* const* d_in, const int* in_sizes, int n_in,
                              void* d_out, int out_size, void* d_ws, size_t ws_size,
                              hipStream_t stream) {
    (void)in_sizes; (void)n_in; (void)out_size; (void)ws_size;
    const float* x  = (const float*)d_in[0];
    const float* wq = (const float*)d_in[1];
    const float* bq = (const float*)d_in[2];
    const float* wk = (const float*)d_in[3];
    const float* bk = (const float*)d_in[4];
    const float* wv = (const float*)d_in[5];
    const float* bv = (const float*)d_in[6];
    const float* wo = (const float*)d_in[7];
    const float* bo = (const float*)d_in[8];
    float* out = (float*)d_out;

    char* ws = (char*)d_ws;
    __hip_bfloat16* xb   = (__hip_bfloat16*)(ws + 0);          // 16.8 MB  (4096x2048)
    __hip_bfloat16* AO   = xb;                                  // alias (xb dead after KV GEMM)
    __hip_bfloat16* wqt  = (__hip_bfloat16*)(ws + 16777216);   // 8.4 MB
    __hip_bfloat16* wkvt = (__hip_bfloat16*)(ws + 25165824);   // 2.1 MB
    __hip_bfloat16* wot  = (__hip_bfloat16*)(ws + 27262976);   // 8.4 MB
    __hip_bfloat16* Qlin = (__hip_bfloat16*)(ws + 35651584);   // 16.8 MB
    __hip_bfloat16* KVlin= (__hip_bfloat16*)(ws + 52428800);   // 4.2 MB
    __hip_bfloat16* Qb   = (__hip_bfloat16*)(ws + 56623104);   // 16.8 MB
    __hip_bfloat16* Kb   = (__hip_bfloat16*)(ws + 73400320);   // 2.1 MB
    __hip_bfloat16* VT   = (__hip_bfloat16*)(ws + 75497472);   // 2.1 MB
    float*          bkv  = (float*)(ws + 77594624);            // 2 KB

    cast_f32_bf16_k<<<8192, 256, 0, stream>>>(x, xb, 2097152);
    transpose_cast_k<<<dim3(64, 64), 256, 0, stream>>>(wq, wqt, 2048, 2048, 0);
    transpose_cast_k<<<dim3(8, 64), 256, 0, stream>>>(wk, wkvt, 2048, 256, 0);
    transpose_cast_k<<<dim3(8, 64), 256, 0, stream>>>(wv, wkvt, 2048, 256, 256);
    transpose_cast_k<<<dim3(64, 64), 256, 0, stream>>>(wo, wot, 2048, 2048, 0);
    concat_bias_k<<<1, 512, 0, stream>>>(bk, bv, bkv);
    gemm_bt_k<__hip_bfloat16><<<dim3(16, 32), 256, 0, stream>>>(xb, wqt, bq, Qlin, 4096, 2048, 2048);
    gemm_bt_k<__hip_bfloat16><<<dim3(4, 32), 256, 0, stream>>>(xb, wkvt, bkv, KVlin, 4096, 512, 2048);
    rope_k<<<16384, 256, 0, stream>>>(Qlin, Qb, 16, 2048, 0.0078125f);
    rope_k<<<2048, 256, 0, stream>>>(KVlin, Kb, 2, 512, 1.0f);
    transpose_v_k<<<dim3(4, 32, 8), 256, 0, stream>>>(KVlin, VT);
    attn_k<<<dim3(64, 16), 256, 0, stream>>>(Qb, Kb, VT, AO);
    gemm_bt_k<float><<<dim3(16, 32), 256, 0, stream>>>(AO, wot, bo, out, 4096, 2048, 2048);
}

// Round 4
// 360.144 us; speedup vs baseline: 1.5033x; 1.5033x over previous
//
#include <hip/hip_runtime.h>
#include <hip/hip_bf16.h>
#include <type_traits>

// Problem constants: B=4, S=1024, D=2048, H=16, G=2, HD=128
typedef __attribute__((ext_vector_type(8))) __bf16 bf16x8;
typedef __attribute__((ext_vector_type(4))) float floatx4;

__device__ inline floatx4 mfma_bf16(bf16x8 a, bf16x8 b, floatx4 c) {
    return __builtin_amdgcn_mfma_f32_16x16x32_bf16(a, b, c, 0, 0, 0);
}

__device__ inline void g2l16(const __hip_bfloat16* g, __hip_bfloat16* l) {
    __builtin_amdgcn_global_load_lds(
        (const __attribute__((address_space(1))) void*)g,
        (__attribute__((address_space(3))) void*)l, 16, 0, 0);
}

// ---------------- cast f32 -> bf16 (vectorized) ----------------
__global__ void cast_f32_bf16_k(const float* __restrict__ in,
                                __hip_bfloat16* __restrict__ out, int n4) {
    int i = blockIdx.x * blockDim.x + threadIdx.x;
    if (i < n4) {
        float4 v = ((const float4*)in)[i];
        ushort4 u;
        __hip_bfloat16 a0 = __float2bfloat16(v.x), a1 = __float2bfloat16(v.y);
        __hip_bfloat16 a2 = __float2bfloat16(v.z), a3 = __float2bfloat16(v.w);
        u.x = *(unsigned short*)&a0; u.y = *(unsigned short*)&a1;
        u.z = *(unsigned short*)&a2; u.w = *(unsigned short*)&a3;
        ((ushort4*)out)[i] = u;
    }
}

// ---------------- transpose + cast: W(R,C) f32 -> Wt(C,R) bf16 ----------------
__global__ void transpose_cast_k(const float* __restrict__ W,
                                 __hip_bfloat16* __restrict__ Wt,
                                 int R, int C, int row_off) {
    __shared__ float tile[32][33];
    int c0 = blockIdx.x * 32, r0 = blockIdx.y * 32;
    int tx = threadIdx.x & 31, ty0 = threadIdx.x >> 5;
#pragma unroll
    for (int i = 0; i < 4; i++) {
        int ty = ty0 + i * 8;
        tile[ty][tx] = W[(size_t)(r0 + ty) * C + c0 + tx];
    }
    __syncthreads();
#pragma unroll
    for (int i = 0; i < 4; i++) {
        int ty = ty0 + i * 8;
        Wt[(size_t)(row_off + c0 + ty) * R + r0 + tx] = __float2bfloat16(tile[tx][ty]);
    }
}

__global__ void concat_bias_k(const float* __restrict__ a,
                              const float* __restrict__ b,
                              float* __restrict__ out) {
    int i = threadIdx.x;
    out[i] = (i < 256) ? a[i] : b[i - 256];
}

// ---------------- GEMM: C(M,N) = A(M,K) @ Bt(N,K)^T + bias, bf16 in, OUT_T out ----
template <typename OUT_T>
__global__ __launch_bounds__(256) void gemm_bt_k(
    const __hip_bfloat16* __restrict__ A,
    const __hip_bfloat16* __restrict__ Bt,
    const float* __restrict__ bias,
    OUT_T* __restrict__ C,
    int M, int N, int K) {
    __shared__ alignas(16) __hip_bfloat16 As[128 * 32];
    __shared__ alignas(16) __hip_bfloat16 Bs[128 * 32];
    const int t = threadIdx.x;
    const int lane = t & 63;
    const int w = t >> 6;
    const int wm = w & 1, wn = w >> 1;
    const int quad = lane >> 4, l16 = lane & 15;
    const int bm = blockIdx.y, bn = blockIdx.x;
    const int r_ = t >> 2, kc_ = t & 3;

    const __hip_bfloat16* gA = A + (size_t)(bm * 128 + r_) * K + kc_ * 8;
    const __hip_bfloat16* gB = Bt + (size_t)(bn * 128 + r_) * K + kc_ * 8;

    floatx4 acc[4][4] = {};

    for (int kt = 0; kt < K; kt += 32) {
        g2l16(gA + kt, As + t * 8);
        g2l16(gA + kt + (size_t)64 * K, As + (t + 256) * 8);
        g2l16(gB + kt, Bs + t * 8);
        g2l16(gB + kt + (size_t)64 * K, Bs + (t + 256) * 8);
        __syncthreads();
        bf16x8 af[4], bfr[4];
#pragma unroll
        for (int mi = 0; mi < 4; mi++)
            af[mi] = *(const bf16x8*)(As + (wm * 64 + mi * 16 + l16) * 32 + quad * 8);
#pragma unroll
        for (int ni = 0; ni < 4; ni++)
            bfr[ni] = *(const bf16x8*)(Bs + (wn * 64 + ni * 16 + l16) * 32 + quad * 8);
#pragma unroll
        for (int mi = 0; mi < 4; mi++)
#pragma unroll
            for (int ni = 0; ni < 4; ni++)
                acc[mi][ni] = mfma_bf16(af[mi], bfr[ni], acc[mi][ni]);
        __syncthreads();
    }

#pragma unroll
    for (int mi = 0; mi < 4; mi++) {
        int row0 = bm * 128 + wm * 64 + mi * 16 + quad * 4;
#pragma unroll
        for (int ni = 0; ni < 4; ni++) {
            int col = bn * 128 + wn * 64 + ni * 16 + l16;
            float bv = bias[col];
#pragma unroll
            for (int r = 0; r < 4; r++) {
                float v = acc[mi][ni][r] + bv;
                if constexpr (std::is_same<OUT_T, float>::value)
                    C[(size_t)(row0 + r) * N + col] = v;
                else
                    C[(size_t)(row0 + r) * N + col] = __float2bfloat16(v);
            }
        }
    }
}

// ---------------- RoPE + relayout ----------------
__global__ void rope_k(const __hip_bfloat16* __restrict__ in,
                       __hip_bfloat16* __restrict__ out,
                       int NH, int in_ld, float scale) {
    int idx = blockIdx.x * 256 + threadIdx.x;
    int j = idx & 63;
    int s = (idx >> 6) & 1023;
    int bh = idx >> 16;
    int b = bh / NH, h = bh % NH;
    float inv_freq = powf(10000.f, -(float)j * (1.f / 64.f));
    float ang = (float)s * inv_freq;
    float cs = cosf(ang), sn = sinf(ang);
    const __hip_bfloat16* ip = in + (size_t)(b * 1024 + s) * in_ld + h * 128;
    float q0 = __bfloat162float(ip[j]);
    float q1 = __bfloat162float(ip[j + 64]);
    __hip_bfloat16* op = out + ((size_t)(b * NH + h) * 1024 + s) * 128;
    op[j]      = __float2bfloat16((q0 * cs - q1 * sn) * scale);
    op[j + 64] = __float2bfloat16((q1 * cs + q0 * sn) * scale);
}

// V part of KVlin (cols 256..511) -> VT (B, G, 128, 1024)
__global__ void transpose_v_k(const __hip_bfloat16* __restrict__ KVlin,
                              __hip_bfloat16* __restrict__ VT) {
    __shared__ __hip_bfloat16 tile[32][33];
    int bg = blockIdx.z;
    int b = bg >> 1, g = bg & 1;
    int s0 = blockIdx.y * 32, d0 = blockIdx.x * 32;
    int tx = threadIdx.x & 31, ty0 = threadIdx.x >> 5;
#pragma unroll
    for (int i = 0; i < 4; i++) {
        int ty = ty0 + i * 8;
        tile[ty][tx] = KVlin[(size_t)(b * 1024 + s0 + ty) * 512 + 256 + g * 128 + d0 + tx];
    }
    __syncthreads();
#pragma unroll
    for (int i = 0; i < 4; i++) {
        int ty = ty0 + i * 8;
        VT[((size_t)(b * 2 + g) * 128 + d0 + ty) * 1024 + s0 + tx] = tile[tx][ty];
    }
}

// ---------------- flash attention v4: m97-style staged structure ----------------
// Block = 1 head x 128 q-rows (4 waves x 32). KV tile 64: K(64x128)+V(128x64)
// staged via global_load_lds with XOR chunk swizzle (conflict-free b128 reads),
// 2 barriers/iter, 64 MFMA/wave/iter (32 QK + 32 PV) vs 8 staging loads/thread.
// Softmax: no max subtraction (|s| ~< 1 by construction), lane-local l.
__global__ __launch_bounds__(256, 2) void attn_k(
    const __hip_bfloat16* __restrict__ Qb,
    const __hip_bfloat16* __restrict__ Kb,
    const __hip_bfloat16* __restrict__ VT,
    __hip_bfloat16* __restrict__ AO) {
    constexpr int PLD = 72;   // P row stride (bf16), 144 B = 9*16 (b128-aligned)
    __shared__ alignas(16) __hip_bfloat16 Ks[64 * 128];   // 16 KB, swizzled
    __shared__ alignas(16) __hip_bfloat16 Vs[128 * 64];   // 16 KB, swizzled
    __shared__ alignas(16) __hip_bfloat16 Ps[4][32 * PLD];// 18 KB

    const int bh = blockIdx.x;          // b*16 + h
    const int b = bh >> 4, h = bh & 15, g = h >> 3;
    const int t = threadIdx.x, lane = t & 63, w = t >> 6;
    const int quad = lane >> 4, l16 = lane & 15;
    const int q0 = blockIdx.y * 128 + w * 32;

    // Q fragments (A-layout): row q0+mi*16+l16, k = kc*32+quad*8
    const __hip_bfloat16* Qp = Qb + ((size_t)bh * 1024 + q0 + l16) * 128 + quad * 8;
    bf16x8 aq[2][4];
#pragma unroll
    for (int mi = 0; mi < 2; mi++)
#pragma unroll
        for (int kc = 0; kc < 4; kc++)
            aq[mi][kc] = *(const bf16x8*)(Qp + mi * 16 * 128 + kc * 32);

    const int bg = b * 2 + g;
    // staging source pointers (XOR-swizzled chunk pick per thread)
    const __hip_bfloat16* Kstage = Kb + (size_t)bg * 1024 * 128
        + (t >> 4) * 128 + ((t & 15) ^ (t >> 4)) * 8;
    const __hip_bfloat16* Vstage = VT + (size_t)bg * 128 * 1024
        + (t >> 3) * 1024 + ((t & 7) ^ ((t >> 3) & 7)) * 8;

    float l_part[2][4] = {};
    floatx4 o[2][8] = {};

    for (int kv = 0; kv < 1024; kv += 64) {
        // ---- stage K (64x128) and V (128x64) into LDS ----
#pragma unroll
        for (int j = 0; j < 4; j++)
            g2l16(Kstage + (size_t)(kv + j * 16) * 128, Ks + (j * 256 + t) * 8);
#pragma unroll
        for (int j = 0; j < 4; j++)
            g2l16(Vstage + (size_t)j * 32 * 1024 + kv, Vs + (j * 256 + t) * 8);
        __syncthreads();

        // ---- QK^T: 32 MFMA ----
        floatx4 s[2][4] = {};
#pragma unroll
        for (int nj = 0; nj < 4; nj++)
#pragma unroll
            for (int kc = 0; kc < 4; kc++) {
                bf16x8 kb = *(const bf16x8*)(Ks + (nj * 16 + l16) * 128
                                             + (((kc * 4 + quad) ^ l16) * 8));
                s[0][nj] = mfma_bf16(aq[0][kc], kb, s[0][nj]);
                s[1][nj] = mfma_bf16(aq[1][kc], kb, s[1][nj]);
            }

        // ---- exp + P to LDS (C-layout -> A-layout round trip) ----
        __hip_bfloat16* pl = Ps[w];
#pragma unroll
        for (int mi = 0; mi < 2; mi++)
#pragma unroll
            for (int nj = 0; nj < 4; nj++)
#pragma unroll
                for (int r = 0; r < 4; r++) {
                    float p = __expf(s[mi][nj][r]);
                    l_part[mi][r] += p;
                    pl[(mi * 16 + quad * 4 + r) * PLD + nj * 16 + l16] =
                        __float2bfloat16(p);
                }
        asm volatile("s_waitcnt lgkmcnt(0)" ::: "memory");

        bf16x8 ap[2][2];
#pragma unroll
        for (int mi = 0; mi < 2; mi++)
#pragma unroll
            for (int kc2 = 0; kc2 < 2; kc2++)
                ap[mi][kc2] = *(const bf16x8*)(pl + (mi * 16 + l16) * PLD
                                               + kc2 * 32 + quad * 8);

        // ---- PV: 32 MFMA ----
#pragma unroll
        for (int ni = 0; ni < 8; ni++)
#pragma unroll
            for (int kc2 = 0; kc2 < 2; kc2++) {
                bf16x8 vb = *(const bf16x8*)(Vs + (ni * 16 + l16) * 64
                                             + (((kc2 * 4 + quad) ^ (l16 & 7)) * 8));
                o[0][ni] = mfma_bf16(ap[0][kc2], vb, o[0][ni]);
                o[1][ni] = mfma_bf16(ap[1][kc2], vb, o[1][ni]);
            }
        __syncthreads();
    }

    // ---- normalize + write ----
#pragma unroll
    for (int mi = 0; mi < 2; mi++)
#pragma unroll
        for (int r = 0; r < 4; r++) {
            float sum = l_part[mi][r];
            sum += __shfl_xor(sum, 1);
            sum += __shfl_xor(sum, 2);
            sum += __shfl_xor(sum, 4);
            sum += __shfl_xor(sum, 8);
            float inv = 1.f / sum;
            size_t srow = (size_t)b * 1024 + q0 + mi * 16 + quad * 4 + r;
#pragma unroll
            for (int ni = 0; ni < 8; ni++)
                AO[srow * 2048 + h * 128 + ni * 16 + l16] =
                    __float2bfloat16(o[mi][ni][r] * inv);
        }
}

extern "C" void kernel_launch(void* const* d_in, const int* in_sizes, int n_in,
                              void* d_out, int out_size, void* d_ws, size_t ws_size,
                              hipStream_t stream) {
    (void)in_sizes; (void)n_in; (void)out_size; (void)ws_size;
    const float* x  = (const float*)d_in[0];
    const float* wq = (const float*)d_in[1];
    const float* bq = (const float*)d_in[2];
    const float* wk = (const float*)d_in[3];
    const float* bk = (const float*)d_in[4];
    const float* wv = (const float*)d_in[5];
    const float* bv = (const float*)d_in[6];
    const float* wo = (const float*)d_in[7];
    const float* bo = (const float*)d_in[8];
    float* out = (float*)d_out;

    char* ws = (char*)d_ws;
    __hip_bfloat16* xb   = (__hip_bfloat16*)(ws + 0);          // 16.8 MB  (4096x2048)
    __hip_bfloat16* AO   = xb;                                  // alias (xb dead after KV GEMM)
    __hip_bfloat16* wqt  = (__hip_bfloat16*)(ws + 16777216);   // 8.4 MB
    __hip_bfloat16* wkvt = (__hip_bfloat16*)(ws + 25165824);   // 2.1 MB
    __hip_bfloat16* wot  = (__hip_bfloat16*)(ws + 27262976);   // 8.4 MB
    __hip_bfloat16* Qlin = (__hip_bfloat16*)(ws + 35651584);   // 16.8 MB
    __hip_bfloat16* KVlin= (__hip_bfloat16*)(ws + 52428800);   // 4.2 MB
    __hip_bfloat16* Qb   = (__hip_bfloat16*)(ws + 56623104);   // 16.8 MB
    __hip_bfloat16* Kb   = (__hip_bfloat16*)(ws + 73400320);   // 2.1 MB
    __hip_bfloat16* VT   = (__hip_bfloat16*)(ws + 75497472);   // 2.1 MB
    float*          bkv  = (float*)(ws + 77594624);            // 2 KB

    cast_f32_bf16_k<<<8192, 256, 0, stream>>>(x, xb, 2097152);
    transpose_cast_k<<<dim3(64, 64), 256, 0, stream>>>(wq, wqt, 2048, 2048, 0);
    transpose_cast_k<<<dim3(8, 64), 256, 0, stream>>>(wk, wkvt, 2048, 256, 0);
    transpose_cast_k<<<dim3(8, 64), 256, 0, stream>>>(wv, wkvt, 2048, 256, 256);
    transpose_cast_k<<<dim3(64, 64), 256, 0, stream>>>(wo, wot, 2048, 2048, 0);
    concat_bias_k<<<1, 512, 0, stream>>>(bk, bv, bkv);
    gemm_bt_k<__hip_bfloat16><<<dim3(16, 32), 256, 0, stream>>>(xb, wqt, bq, Qlin, 4096, 2048, 2048);
    gemm_bt_k<__hip_bfloat16><<<dim3(4, 32), 256, 0, stream>>>(xb, wkvt, bkv, KVlin, 4096, 512, 2048);
    rope_k<<<16384, 256, 0, stream>>>(Qlin, Qb, 16, 2048, 0.0078125f);
    rope_k<<<2048, 256, 0, stream>>>(KVlin, Kb, 2, 512, 1.0f);
    transpose_v_k<<<dim3(4, 32, 8), 256, 0, stream>>>(KVlin, VT);
    attn_k<<<dim3(64, 8), 256, 0, stream>>>(Qb, Kb, VT, AO);
    gemm_bt_k<float><<<dim3(16, 32), 256, 0, stream>>>(AO, wot, bo, out, 4096, 2048, 2048);
}

// Round 5
// 281.390 us; speedup vs baseline: 1.9241x; 1.2799x over previous
//
#include <hip/hip_runtime.h>
#include <hip/hip_bf16.h>
#include <type_traits>

// Problem constants: B=4, S=1024, D=2048, H=16, G=2, HD=128
typedef __attribute__((ext_vector_type(8))) __bf16 bf16x8;
typedef __attribute__((ext_vector_type(4))) float floatx4;

__device__ inline floatx4 mfma_bf16(bf16x8 a, bf16x8 b, floatx4 c) {
    return __builtin_amdgcn_mfma_f32_16x16x32_bf16(a, b, c, 0, 0, 0);
}

__device__ inline void g2l16(const __hip_bfloat16* g, __hip_bfloat16* l) {
    __builtin_amdgcn_global_load_lds(
        (const __attribute__((address_space(1))) void*)g,
        (__attribute__((address_space(3))) void*)l, 16, 0, 0);
}

// ---------------- cast f32 -> bf16 (vectorized) ----------------
__global__ void cast_f32_bf16_k(const float* __restrict__ in,
                                __hip_bfloat16* __restrict__ out, int n4) {
    int i = blockIdx.x * blockDim.x + threadIdx.x;
    if (i < n4) {
        float4 v = ((const float4*)in)[i];
        ushort4 u;
        __hip_bfloat16 a0 = __float2bfloat16(v.x), a1 = __float2bfloat16(v.y);
        __hip_bfloat16 a2 = __float2bfloat16(v.z), a3 = __float2bfloat16(v.w);
        u.x = *(unsigned short*)&a0; u.y = *(unsigned short*)&a1;
        u.z = *(unsigned short*)&a2; u.w = *(unsigned short*)&a3;
        ((ushort4*)out)[i] = u;
    }
}

// ---------------- fused prep: all weight transposes + bias concat ----------------
// wq -> wqkvt rows 0..2047, wk -> 2048..2303, wv -> 2304..2559, wo -> wot.
// blocks: [0,4096) wq, [4096,4608) wk, [4608,5120) wv, [5120,9216) wo,
// [9216,9226) bias concat (2560 floats).
__global__ void prep_k(const float* __restrict__ wq, const float* __restrict__ wk,
                       const float* __restrict__ wv, const float* __restrict__ wo,
                       const float* __restrict__ bq, const float* __restrict__ bk,
                       const float* __restrict__ bv,
                       __hip_bfloat16* __restrict__ wqkvt,
                       __hip_bfloat16* __restrict__ wot,
                       float* __restrict__ bqkv) {
    int bid = blockIdx.x;
    if (bid >= 9216) {
        int i = (bid - 9216) * 256 + threadIdx.x;
        if (i < 2560)
            bqkv[i] = (i < 2048) ? bq[i] : (i < 2304 ? bk[i - 2048] : bv[i - 2304]);
        return;
    }
    const float* W; __hip_bfloat16* Wt; int C, row_off, cb, rb;
    if (bid < 4096)      { W = wq; Wt = wqkvt; C = 2048; row_off = 0;
                           cb = bid & 63; rb = bid >> 6; }
    else if (bid < 4608) { W = wk; Wt = wqkvt; C = 256;  row_off = 2048;
                           int id = bid - 4096; cb = id & 7; rb = id >> 3; }
    else if (bid < 5120) { W = wv; Wt = wqkvt; C = 256;  row_off = 2304;
                           int id = bid - 4608; cb = id & 7; rb = id >> 3; }
    else                 { W = wo; Wt = wot;   C = 2048; row_off = 0;
                           int id = bid - 5120; cb = id & 63; rb = id >> 6; }
    __shared__ float tile[32][33];
    int c0 = cb * 32, r0 = rb * 32;
    int tx = threadIdx.x & 31, ty0 = threadIdx.x >> 5;
#pragma unroll
    for (int i = 0; i < 4; i++) {
        int ty = ty0 + i * 8;
        tile[ty][tx] = W[(size_t)(r0 + ty) * C + c0 + tx];
    }
    __syncthreads();
#pragma unroll
    for (int i = 0; i < 4; i++) {
        int ty = ty0 + i * 8;
        Wt[(size_t)(row_off + c0 + ty) * 2048 + r0 + tx] = __float2bfloat16(tile[tx][ty]);
    }
}

// ---------------- fused QKV GEMM + RoPE epilogue ----------------
// A(4096,2048) @ wqkvt(2560,2048)^T. Wave w owns rows w*32..+31 x all 128 cols
// so each lane holds both halves of a RoPE pair (acc[.][ni] / acc[.][ni+4]).
// bn<16: Q head (RoPE, *1/128) -> Qb(B*H,S,128); bn 16/17: K group (RoPE) ->
// Kb(B*G,S,128); bn 18/19: V group -> Vlin(4096,256).
// LDS XOR chunk swizzle: chunk c of row r stored at position c^((r>>1)&3)
// -> b128 frag reads are 2-way (free) instead of 8-way.
__global__ __launch_bounds__(256) void gemm_qkv_k(
    const __hip_bfloat16* __restrict__ A,
    const __hip_bfloat16* __restrict__ Bt,
    const float* __restrict__ bias,
    __hip_bfloat16* __restrict__ Qb,
    __hip_bfloat16* __restrict__ Kb,
    __hip_bfloat16* __restrict__ Vlin) {
    __shared__ alignas(16) __hip_bfloat16 As[128 * 32];
    __shared__ alignas(16) __hip_bfloat16 Bs[128 * 32];
    const int t = threadIdx.x, lane = t & 63, w = t >> 6;
    const int quad = lane >> 4, l16 = lane & 15;
    const int bm = blockIdx.y, bn = blockIdx.x;
    const int r_ = t >> 2;
    const int kc_ = (t & 3) ^ ((t >> 3) & 3);   // swizzled source chunk
    const int swz = (l16 >> 1) & 3;

    const __hip_bfloat16* gA = A + (size_t)(bm * 128 + r_) * 2048 + kc_ * 8;
    const __hip_bfloat16* gB = Bt + (size_t)(bn * 128 + r_) * 2048 + kc_ * 8;

    floatx4 acc[2][8] = {};

    for (int kt = 0; kt < 2048; kt += 32) {
        g2l16(gA + kt, As + t * 8);
        g2l16(gA + kt + 64 * 2048, As + (t + 256) * 8);
        g2l16(gB + kt, Bs + t * 8);
        g2l16(gB + kt + 64 * 2048, Bs + (t + 256) * 8);
        __syncthreads();
        bf16x8 af[2], bfr[8];
#pragma unroll
        for (int mi = 0; mi < 2; mi++)
            af[mi] = *(const bf16x8*)(As + (w * 32 + mi * 16 + l16) * 32 + (quad ^ swz) * 8);
#pragma unroll
        for (int ni = 0; ni < 8; ni++)
            bfr[ni] = *(const bf16x8*)(Bs + (ni * 16 + l16) * 32 + (quad ^ swz) * 8);
#pragma unroll
        for (int mi = 0; mi < 2; mi++)
#pragma unroll
            for (int ni = 0; ni < 8; ni++)
                acc[mi][ni] = mfma_bf16(af[mi], bfr[ni], acc[mi][ni]);
        __syncthreads();
    }

    const int row_base = bm * 128 + w * 32 + quad * 4;
    if (bn < 18) {
        // Q (bn<16) or K (bn 16/17): RoPE pairs (j, j+64), j = ni*16+l16, ni<4
        const float scale = (bn < 16) ? 0.0078125f : 1.0f;
        __hip_bfloat16* dst = (bn < 16) ? Qb : Kb;
        const int nh = (bn < 16) ? 16 : 2;
        const int hh = (bn < 16) ? bn : (bn - 16);
#pragma unroll
        for (int ni = 0; ni < 4; ni++) {
            int j = ni * 16 + l16;
            float invf = __expf(-(float)j * (9.210340371976184f / 64.f)); // 10000^{-j/64}
            float bj  = bias[bn * 128 + j];
            float bj2 = bias[bn * 128 + j + 64];
#pragma unroll
            for (int mi = 0; mi < 2; mi++)
#pragma unroll
                for (int r = 0; r < 4; r++) {
                    int row = row_base + mi * 16 + r;
                    int b = row >> 10, s = row & 1023;
                    float vj  = acc[mi][ni][r] + bj;
                    float vj2 = acc[mi][ni + 4][r] + bj2;
                    float sn, cs;
                    __sincosf((float)s * invf, &sn, &cs);
                    __hip_bfloat16* op = dst + ((size_t)(b * nh + hh) * 1024 + s) * 128;
                    op[j]      = __float2bfloat16((vj * cs - vj2 * sn) * scale);
                    op[j + 64] = __float2bfloat16((vj2 * cs + vj * sn) * scale);
                }
        }
    } else {
        int g = bn - 18;
#pragma unroll
        for (int ni = 0; ni < 8; ni++) {
            int col = ni * 16 + l16;
            float bv = bias[bn * 128 + col];
#pragma unroll
            for (int mi = 0; mi < 2; mi++)
#pragma unroll
                for (int r = 0; r < 4; r++) {
                    int row = row_base + mi * 16 + r;
                    Vlin[(size_t)row * 256 + g * 128 + col] =
                        __float2bfloat16(acc[mi][ni][r] + bv);
                }
        }
    }
}

// ---------------- GEMM: C(M,N) = A(M,K) @ Bt(N,K)^T + bias (out proj) ----------
template <typename OUT_T>
__global__ __launch_bounds__(256) void gemm_bt_k(
    const __hip_bfloat16* __restrict__ A,
    const __hip_bfloat16* __restrict__ Bt,
    const float* __restrict__ bias,
    OUT_T* __restrict__ C,
    int M, int N, int K) {
    __shared__ alignas(16) __hip_bfloat16 As[128 * 32];
    __shared__ alignas(16) __hip_bfloat16 Bs[128 * 32];
    const int t = threadIdx.x;
    const int lane = t & 63;
    const int w = t >> 6;
    const int wm = w & 1, wn = w >> 1;
    const int quad = lane >> 4, l16 = lane & 15;
    const int bm = blockIdx.y, bn = blockIdx.x;
    const int r_ = t >> 2;
    const int kc_ = (t & 3) ^ ((t >> 3) & 3);   // swizzled source chunk
    const int swz = (l16 >> 1) & 3;

    const __hip_bfloat16* gA = A + (size_t)(bm * 128 + r_) * K + kc_ * 8;
    const __hip_bfloat16* gB = Bt + (size_t)(bn * 128 + r_) * K + kc_ * 8;

    floatx4 acc[4][4] = {};

    for (int kt = 0; kt < K; kt += 32) {
        g2l16(gA + kt, As + t * 8);
        g2l16(gA + kt + (size_t)64 * K, As + (t + 256) * 8);
        g2l16(gB + kt, Bs + t * 8);
        g2l16(gB + kt + (size_t)64 * K, Bs + (t + 256) * 8);
        __syncthreads();
        bf16x8 af[4], bfr[4];
#pragma unroll
        for (int mi = 0; mi < 4; mi++)
            af[mi] = *(const bf16x8*)(As + (wm * 64 + mi * 16 + l16) * 32 + (quad ^ swz) * 8);
#pragma unroll
        for (int ni = 0; ni < 4; ni++)
            bfr[ni] = *(const bf16x8*)(Bs + (wn * 64 + ni * 16 + l16) * 32 + (quad ^ swz) * 8);
#pragma unroll
        for (int mi = 0; mi < 4; mi++)
#pragma unroll
            for (int ni = 0; ni < 4; ni++)
                acc[mi][ni] = mfma_bf16(af[mi], bfr[ni], acc[mi][ni]);
        __syncthreads();
    }

#pragma unroll
    for (int mi = 0; mi < 4; mi++) {
        int row0 = bm * 128 + wm * 64 + mi * 16 + quad * 4;
#pragma unroll
        for (int ni = 0; ni < 4; ni++) {
            int col = bn * 128 + wn * 64 + ni * 16 + l16;
            float bv = bias[col];
#pragma unroll
            for (int r = 0; r < 4; r++) {
                float v = acc[mi][ni][r] + bv;
                if constexpr (std::is_same<OUT_T, float>::value)
                    C[(size_t)(row0 + r) * N + col] = v;
                else
                    C[(size_t)(row0 + r) * N + col] = __float2bfloat16(v);
            }
        }
    }
}

// V part of Vlin (4096 x 256) -> VT (B, G, 128, 1024)
__global__ void transpose_v_k(const __hip_bfloat16* __restrict__ Vlin,
                              __hip_bfloat16* __restrict__ VT) {
    __shared__ __hip_bfloat16 tile[32][33];
    int bg = blockIdx.z;
    int b = bg >> 1, g = bg & 1;
    int s0 = blockIdx.y * 32, d0 = blockIdx.x * 32;
    int tx = threadIdx.x & 31, ty0 = threadIdx.x >> 5;
#pragma unroll
    for (int i = 0; i < 4; i++) {
        int ty = ty0 + i * 8;
        tile[ty][tx] = Vlin[(size_t)(b * 1024 + s0 + ty) * 256 + g * 128 + d0 + tx];
    }
    __syncthreads();
#pragma unroll
    for (int i = 0; i < 4; i++) {
        int ty = ty0 + i * 8;
        VT[((size_t)(b * 2 + g) * 128 + d0 + ty) * 1024 + s0 + tx] = tile[tx][ty];
    }
}

// ---------------- flash attention (v4, m97-style staged) ----------------
__global__ __launch_bounds__(256, 2) void attn_k(
    const __hip_bfloat16* __restrict__ Qb,
    const __hip_bfloat16* __restrict__ Kb,
    const __hip_bfloat16* __restrict__ VT,
    __hip_bfloat16* __restrict__ AO) {
    constexpr int PLD = 72;
    __shared__ alignas(16) __hip_bfloat16 Ks[64 * 128];
    __shared__ alignas(16) __hip_bfloat16 Vs[128 * 64];
    __shared__ alignas(16) __hip_bfloat16 Ps[4][32 * PLD];

    const int bh = blockIdx.x;          // b*16 + h
    const int b = bh >> 4, h = bh & 15, g = h >> 3;
    const int t = threadIdx.x, lane = t & 63, w = t >> 6;
    const int quad = lane >> 4, l16 = lane & 15;
    const int q0 = blockIdx.y * 128 + w * 32;

    const __hip_bfloat16* Qp = Qb + ((size_t)bh * 1024 + q0 + l16) * 128 + quad * 8;
    bf16x8 aq[2][4];
#pragma unroll
    for (int mi = 0; mi < 2; mi++)
#pragma unroll
        for (int kc = 0; kc < 4; kc++)
            aq[mi][kc] = *(const bf16x8*)(Qp + mi * 16 * 128 + kc * 32);

    const int bg = b * 2 + g;
    const __hip_bfloat16* Kstage = Kb + (size_t)bg * 1024 * 128
        + (t >> 4) * 128 + ((t & 15) ^ (t >> 4)) * 8;
    const __hip_bfloat16* Vstage = VT + (size_t)bg * 128 * 1024
        + (t >> 3) * 1024 + ((t & 7) ^ ((t >> 3) & 7)) * 8;

    float l_part[2][4] = {};
    floatx4 o[2][8] = {};

    for (int kv = 0; kv < 1024; kv += 64) {
#pragma unroll
        for (int j = 0; j < 4; j++)
            g2l16(Kstage + (size_t)(kv + j * 16) * 128, Ks + (j * 256 + t) * 8);
#pragma unroll
        for (int j = 0; j < 4; j++)
            g2l16(Vstage + (size_t)j * 32 * 1024 + kv, Vs + (j * 256 + t) * 8);
        __syncthreads();

        floatx4 s[2][4] = {};
#pragma unroll
        for (int nj = 0; nj < 4; nj++)
#pragma unroll
            for (int kc = 0; kc < 4; kc++) {
                bf16x8 kb = *(const bf16x8*)(Ks + (nj * 16 + l16) * 128
                                             + (((kc * 4 + quad) ^ l16) * 8));
                s[0][nj] = mfma_bf16(aq[0][kc], kb, s[0][nj]);
                s[1][nj] = mfma_bf16(aq[1][kc], kb, s[1][nj]);
            }

        __hip_bfloat16* pl = Ps[w];
#pragma unroll
        for (int mi = 0; mi < 2; mi++)
#pragma unroll
            for (int nj = 0; nj < 4; nj++)
#pragma unroll
                for (int r = 0; r < 4; r++) {
                    float p = __expf(s[mi][nj][r]);
                    l_part[mi][r] += p;
                    pl[(mi * 16 + quad * 4 + r) * PLD + nj * 16 + l16] =
                        __float2bfloat16(p);
                }
        asm volatile("s_waitcnt lgkmcnt(0)" ::: "memory");

        bf16x8 ap[2][2];
#pragma unroll
        for (int mi = 0; mi < 2; mi++)
#pragma unroll
            for (int kc2 = 0; kc2 < 2; kc2++)
                ap[mi][kc2] = *(const bf16x8*)(pl + (mi * 16 + l16) * PLD
                                               + kc2 * 32 + quad * 8);

#pragma unroll
        for (int ni = 0; ni < 8; ni++)
#pragma unroll
            for (int kc2 = 0; kc2 < 2; kc2++) {
                bf16x8 vb = *(const bf16x8*)(Vs + (ni * 16 + l16) * 64
                                             + (((kc2 * 4 + quad) ^ (l16 & 7)) * 8));
                o[0][ni] = mfma_bf16(ap[0][kc2], vb, o[0][ni]);
                o[1][ni] = mfma_bf16(ap[1][kc2], vb, o[1][ni]);
            }
        __syncthreads();
    }

#pragma unroll
    for (int mi = 0; mi < 2; mi++)
#pragma unroll
        for (int r = 0; r < 4; r++) {
            float sum = l_part[mi][r];
            sum += __shfl_xor(sum, 1);
            sum += __shfl_xor(sum, 2);
            sum += __shfl_xor(sum, 4);
            sum += __shfl_xor(sum, 8);
            float inv = 1.f / sum;
            size_t srow = (size_t)b * 1024 + q0 + mi * 16 + quad * 4 + r;
#pragma unroll
            for (int ni = 0; ni < 8; ni++)
                AO[srow * 2048 + h * 128 + ni * 16 + l16] =
                    __float2bfloat16(o[mi][ni][r] * inv);
        }
}

extern "C" void kernel_launch(void* const* d_in, const int* in_sizes, int n_in,
                              void* d_out, int out_size, void* d_ws, size_t ws_size,
                              hipStream_t stream) {
    (void)in_sizes; (void)n_in; (void)out_size; (void)ws_size;
    const float* x  = (const float*)d_in[0];
    const float* wq = (const float*)d_in[1];
    const float* bq = (const float*)d_in[2];
    const float* wk = (const float*)d_in[3];
    const float* bk = (const float*)d_in[4];
    const float* wv = (const float*)d_in[5];
    const float* bv = (const float*)d_in[6];
    const float* wo = (const float*)d_in[7];
    const float* bo = (const float*)d_in[8];
    float* out = (float*)d_out;

    char* ws = (char*)d_ws;
    __hip_bfloat16* xb    = (__hip_bfloat16*)(ws + 0);          // 16.8 MB (4096x2048)
    __hip_bfloat16* AO    = xb;                                  // alias (xb dead after QKV gemm)
    __hip_bfloat16* wqkvt = (__hip_bfloat16*)(ws + 16777216);   // 10.5 MB (2560x2048)
    __hip_bfloat16* wot   = (__hip_bfloat16*)(ws + 27262976);   // 8.4 MB  (2048x2048)
    __hip_bfloat16* Qb    = (__hip_bfloat16*)(ws + 35651584);   // 16.8 MB (B*H,S,128)
    __hip_bfloat16* Kb    = (__hip_bfloat16*)(ws + 52428800);   // 2.1 MB  (B*G,S,128)
    __hip_bfloat16* Vlin  = (__hip_bfloat16*)(ws + 54525952);   // 2.1 MB  (4096x256)
    __hip_bfloat16* VT    = (__hip_bfloat16*)(ws + 56623104);   // 2.1 MB  (B*G,128,S)
    float*          bqkv  = (float*)(ws + 58720256);            // 10 KB   (2560)

    cast_f32_bf16_k<<<8192, 256, 0, stream>>>(x, xb, 2097152);
    prep_k<<<9226, 256, 0, stream>>>(wq, wk, wv, wo, bq, bk, bv, wqkvt, wot, bqkv);
    gemm_qkv_k<<<dim3(20, 32), 256, 0, stream>>>(xb, wqkvt, bqkv, Qb, Kb, Vlin);
    transpose_v_k<<<dim3(4, 32, 8), 256, 0, stream>>>(Vlin, VT);
    attn_k<<<dim3(64, 8), 256, 0, stream>>>(Qb, Kb, VT, AO);
    gemm_bt_k<float><<<dim3(16, 32), 256, 0, stream>>>(AO, wot, bo, out, 4096, 2048, 2048);
}